// Round 12
// baseline (649.166 us; speedup 1.0000x reference)
//
#include <hip/hip_runtime.h>
#include <cstdint>
#include <cstddef>

#define N_NEU 2048
#define D_IN  1024
#define T_STEPS 64

typedef _Float16 f16x8 __attribute__((ext_vector_type(8)));
typedef _Float16 f16x4 __attribute__((ext_vector_type(4)));
typedef float    f32x4 __attribute__((ext_vector_type(4)));
typedef unsigned u32x4 __attribute__((ext_vector_type(4)));

#define MFMA16(a, b, c) __builtin_amdgcn_mfma_f32_16x16x32_f16((a), (b), (c), 0, 0, 0)

// ---------------- ws layout (bytes) ----------------
// Wh   [2048][2048] f16   @ 0       (8 MB)
// Wl   [2048][2048] f16   @ 8 MB    (8 MB)
// Iext [256][2048]  f32   @ 16 MB   (2 MB)
// bmv  u64[2][256][64]    @ 18 MB   (256 KB)  (tag<<32)|bits: word (row, n/32), bit n%32

// 8 bits -> 8 f16 (0.0 / 1.0)
__device__ inline f16x8 expand8(unsigned b) {
  u32x4 t;
  t[0] = ((b & 1u)   ? 0x3C00u : 0u) | ((b & 2u)   ? 0x3C000000u : 0u);
  t[1] = ((b & 4u)   ? 0x3C00u : 0u) | ((b & 8u)   ? 0x3C000000u : 0u);
  t[2] = ((b & 16u)  ? 0x3C00u : 0u) | ((b & 32u)  ? 0x3C000000u : 0u);
  t[3] = ((b & 64u)  ? 0x3C00u : 0u) | ((b & 128u) ? 0x3C000000u : 0u);
  return __builtin_bit_cast(f16x8, t);
}

// Split W_eff = adj*mask into f16 hi + f16 lo' (w ~= hi + lo'/4096). Zeroes bmv (replay!).
__global__ __launch_bounds__(256) void k_wsplit(const float* __restrict__ adj,
                                                const float* __restrict__ mask,
                                                _Float16* __restrict__ Wh,
                                                _Float16* __restrict__ Wl,
                                                unsigned long long* __restrict__ bmv) {
  const int idx = blockIdx.x * 256 + threadIdx.x;
  if (idx < 2 * 256 * 64) bmv[idx] = 0ull;
  const int total4 = (N_NEU * N_NEU) / 4;
  for (int i = idx; i < total4; i += gridDim.x * 256) {
    float4 a = ((const float4*)adj)[i];
    float4 m = ((const float4*)mask)[i];
    float w0 = a.x * m.x, w1 = a.y * m.y, w2 = a.z * m.z, w3 = a.w * m.w;
    f16x4 h, lo;
    h[0] = (_Float16)w0; lo[0] = (_Float16)((w0 - (float)h[0]) * 4096.0f);
    h[1] = (_Float16)w1; lo[1] = (_Float16)((w1 - (float)h[1]) * 4096.0f);
    h[2] = (_Float16)w2; lo[2] = (_Float16)((w2 - (float)h[2]) * 4096.0f);
    h[3] = (_Float16)w3; lo[3] = (_Float16)((w3 - (float)h[3]) * 4096.0f);
    ((f16x4*)Wh)[i] = h;
    ((f16x4*)Wl)[i] = lo;
  }
}

// I_ext = ext @ W_in^T + b_in, plain fp32. Proven absmax 0.0 (r1/r5-r11).
__global__ __launch_bounds__(256) void k_iext(const float* __restrict__ ext,
                                              const float* __restrict__ Win,
                                              const float* __restrict__ bin,
                                              float* __restrict__ Iext) {
  __shared__ float At[32][68];
  __shared__ float Bt[32][68];
  const int tid = threadIdx.x;
  const int b0 = (blockIdx.x & 3) * 64;
  const int n0 = (blockIdx.x >> 2) * 64;
  const int tx = tid & 15, ty = tid >> 4;
  float acc[4][4] = {};
  for (int kt = 0; kt < D_IN / 32; ++kt) {
    const int k0 = kt * 32;
#pragma unroll
    for (int i = 0; i < 8; ++i) {
      int e = tid + i * 256;
      int kk = e & 31, row = e >> 5;
      At[kk][row] = ext[(size_t)(b0 + row) * D_IN + k0 + kk];
      Bt[kk][row] = Win[(size_t)(n0 + row) * D_IN + k0 + kk];
    }
    __syncthreads();
    for (int kk = 0; kk < 32; ++kk) {
      f32x4 a = *(const f32x4*)&At[kk][ty * 4];
      f32x4 b = *(const f32x4*)&Bt[kk][tx * 4];
#pragma unroll
      for (int i = 0; i < 4; ++i)
#pragma unroll
        for (int j = 0; j < 4; ++j) acc[i][j] += a[i] * b[j];
    }
    __syncthreads();
  }
#pragma unroll
  for (int i = 0; i < 4; ++i)
#pragma unroll
    for (int j = 0; j < 4; ++j)
      Iext[(size_t)(b0 + ty * 4 + i) * N_NEU + n0 + tx * 4 + j] = acc[i][j] + bin[n0 + tx * 4 + j];
}

// Persistent fused LIF kernel, dual-group zero-barrier dataflow, 16-wave split-K.
// 256 blocks x 1024 thr (1/CU, 4 waves/SIMD). Block (gp 0..3, ns 0..63): groups gA=gp,
// gB=gp+4 (32 rows) x cols ns*32..+32. Wave kw 0..15 owns K-span kw*128..+128.
// Wh+Wl resident (64 VGPRs). Each thread owns ONE output element (row=tid>>5, col=tid&31).
__global__ __launch_bounds__(1024, 4) void k_fused9(
    const _Float16* __restrict__ Wh, const _Float16* __restrict__ Wl,
    const float* __restrict__ Iext, unsigned long long* __restrict__ bmv,
    float* __restrict__ out) {
  __shared__ float red[8 * 32 * 32];   // 32 KB split-K reduce
  __shared__ unsigned bmA[32 * 64];    // 8 KB group-A spike bits (swizzled)
  __shared__ unsigned bmB[32 * 64];    // 8 KB group-B spike bits

  const int tid = threadIdx.x;
  const int lane = tid & 63;
  const int kw = tid >> 6;        // wave id = split-K index 0..15
  const int l15 = lane & 15;
  const int klo = lane >> 4;      // 0..3
  const int sh = klo * 8;
  const int gp = blockIdx.x >> 6; // 0..3
  const int ns = blockIdx.x & 63; // 0..63
  const int n0 = ns * 32;
  const int gA = gp, gB = gp + 4;
  const int orow = tid >> 5, ocol = tid & 31;  // this thread's output element
  const float inv4096 = 1.0f / 4096.0f;
  const f32x4 z4 = {0.f, 0.f, 0.f, 0.f};

  // ---------- per-thread Iext (one element per group) ----------
  const float IxA = Iext[(size_t)(gA * 32 + orow) * N_NEU + n0 + ocol];
  const float IxB = Iext[(size_t)(gB * 32 + orow) * N_NEU + n0 + ocol];

  // ---------- resident Wh + Wl fragments (128 K per wave) ----------
  const _Float16* whb = Wh + (size_t)(n0 + l15) * N_NEU + kw * 128 + klo * 8;
  const _Float16* wlb = Wl + (size_t)(n0 + l15) * N_NEU + kw * 128 + klo * 8;
  f16x8 whf[2][4], wlf[2][4];
#pragma unroll
  for (int nt = 0; nt < 2; ++nt)
#pragma unroll
    for (int kcl = 0; kcl < 4; ++kcl) {
      whf[nt][kcl] = *(const f16x8*)(whb + nt * 16 * N_NEU + kcl * 32);
      wlf[nt][kcl] = *(const f16x8*)(wlb + nt * 16 * N_NEU + kcl * 32);
    }

  float VA = 0.f, VB = 0.f;
  unsigned cntA = 0u, cntB = 0u;
  unsigned long long vA[2], vB[2];

  // speculative one-shot load of group g's 2048-u64 slab (2 coalesced u64/thread)
  auto spec_issue = [&](int g, int buf, unsigned long long (&v)[2]) {
    const unsigned long long* src = bmv + (size_t)buf * 16384 + (size_t)g * 2048 + tid;
#pragma unroll
    for (int i = 0; i < 2; ++i)
      v[i] = __hip_atomic_load(src + (size_t)i * 1024, __ATOMIC_RELAXED, __HIP_MEMORY_SCOPE_AGENT);
  };
  // validate tags; retry only stale words
  auto check_retry = [&](int g, int buf, unsigned want, unsigned long long (&v)[2]) {
    const unsigned long long* src = bmv + (size_t)buf * 16384 + (size_t)g * 2048 + tid;
    unsigned need = 0u;
#pragma unroll
    for (int i = 0; i < 2; ++i)
      if ((unsigned)(v[i] >> 32) != want) need |= 1u << i;
    while (need) {
      __builtin_amdgcn_s_sleep(2);
#pragma unroll
      for (int i = 0; i < 2; ++i)
        if (need & (1u << i)) {
          v[i] = __hip_atomic_load(src + (size_t)i * 1024,
                                   __ATOMIC_RELAXED, __HIP_MEMORY_SCOPE_AGENT);
          if ((unsigned)(v[i] >> 32) == want) need &= ~(1u << i);
        }
    }
  };
  // stage bits into swizzled LDS: word nsw of row r at [r*64 + (nsw ^ ((r&15)<<2))]
  auto stage = [&](unsigned* bm, const unsigned long long (&v)[2]) {
#pragma unroll
    for (int i = 0; i < 2; ++i) {
      const int w = i * 1024 + tid, r = w >> 6, nsw = w & 63;
      bm[r * 64 + (nsw ^ ((r & 15) << 2))] = (unsigned)v[i];
    }
  };
  // K-loop + 16-way split-K tree -> scalar cI (this thread's output element)
  auto gemm = [&](const unsigned* bm, float& cI_out) {
    f32x4 acch[2][2], accl[2][2];
#pragma unroll
    for (int mt = 0; mt < 2; ++mt)
#pragma unroll
      for (int nt = 0; nt < 2; ++nt) { acch[mt][nt] = z4; accl[mt][nt] = z4; }
#pragma unroll
    for (int mt = 0; mt < 2; ++mt) {
      const int row = mt * 16 + l15;
      const int swz = l15 << 2;
      const u32x4 q = *(const u32x4*)&bm[row * 64 + ((kw * 4) ^ swz)];
#pragma unroll
      for (int kcl = 0; kcl < 4; ++kcl) {
        const f16x8 a = expand8((q[kcl] >> sh) & 0xFFu);
        acch[mt][0] = MFMA16(a, whf[0][kcl], acch[mt][0]);
        accl[mt][0] = MFMA16(a, wlf[0][kcl], accl[mt][0]);
        acch[mt][1] = MFMA16(a, whf[1][kcl], acch[mt][1]);
        accl[mt][1] = MFMA16(a, wlf[1][kcl], accl[mt][1]);
      }
    }
    // fold lo into hi (in place, saves VGPRs)
#pragma unroll
    for (int mt = 0; mt < 2; ++mt)
#pragma unroll
      for (int nt = 0; nt < 2; ++nt) acch[mt][nt] += accl[mt][nt] * inv4096;
    // 16-way tree: waves 8-15 store, 0-7 add, then per-thread 8-partial sum
    const int cbn = lane & 15, rq = (lane >> 4) << 2;
    if (kw >= 8) {
      const int p = kw - 8;
#pragma unroll
      for (int mt = 0; mt < 2; ++mt)
#pragma unroll
        for (int nt = 0; nt < 2; ++nt) {
          const int col = nt * 16 + cbn;
          const int r0 = (mt * 16 + rq) ^ ((col & 7) << 2);
          *(f32x4*)(red + (p * 32 + col) * 32 + r0) = acch[mt][nt];
        }
    }
    __syncthreads();
    if (kw < 8) {
#pragma unroll
      for (int mt = 0; mt < 2; ++mt)
#pragma unroll
        for (int nt = 0; nt < 2; ++nt) {
          const int col = nt * 16 + cbn;
          const int r0 = (mt * 16 + rq) ^ ((col & 7) << 2);
          float* p2 = red + (kw * 32 + col) * 32 + r0;
          f32x4 o = *(const f32x4*)p2;
          o += acch[mt][nt];
          *(f32x4*)p2 = o;
        }
    }
    __syncthreads();
    const int rs = orow ^ ((ocol & 7) << 2);
    float s = 0.0f;
#pragma unroll
    for (int p = 0; p < 8; ++p) s += red[(p * 32 + ocol) * 32 + rs];
    cI_out = s;
  };
  // LIF (scalar state) + tagged spike store (tag and bits in one u64)
  auto lif = [&](float cI, float Ix, float& V, unsigned& cnt, int g, int nbuf,
                 unsigned tag, bool dostore) {
    float I = cI + Ix;
    float v = 0.9f * V + I;
    bool sp = (v - 1.0f) >= 0.0f;
    V = sp ? 0.0f : v;
    cnt += sp ? 1u : 0u;
    if (dostore) {
      unsigned long long ba = __ballot(sp);
      const int rowf = g * 32 + kw * 2;  // lanes 0-31: rowf, lanes 32-63: rowf+1
      const unsigned long long tg = ((unsigned long long)tag) << 32;
      if (lane == 0)
        __hip_atomic_store(bmv + (size_t)nbuf * 16384 + (size_t)rowf * 64 + ns,
                           tg | (unsigned)ba, __ATOMIC_RELAXED, __HIP_MEMORY_SCOPE_AGENT);
      else if (lane == 32)
        __hip_atomic_store(bmv + (size_t)nbuf * 16384 + (size_t)(rowf + 1) * 64 + ns,
                           tg | (unsigned)(ba >> 32), __ATOMIC_RELAXED, __HIP_MEMORY_SCOPE_AGENT);
    }
  };

  // ---------- t = 0: Iext-only LIF; spikes tagged 1 -> buf 1; prefetch A ----------
  lif(0.0f, IxA, VA, cntA, gA, 1, 1u, true);
  lif(0.0f, IxB, VB, cntB, gB, 1, 1u, true);
  spec_issue(gA, 1, vA);

  for (int t = 1; t < T_STEPS; ++t) {
    const int cbuf = t & 1, nbuf = (t + 1) & 1;
    const bool last = (t == T_STEPS - 1);
    float cI;

    // ---- phase A ----
    check_retry(gA, cbuf, (unsigned)t, vA);
    stage(bmA, vA);
    __syncthreads();
    spec_issue(gB, cbuf, vB);            // in flight under gemm(A)
    gemm(bmA, cI);
    lif(cI, IxA, VA, cntA, gA, nbuf, (unsigned)(t + 1), !last);

    // ---- phase B ----
    check_retry(gB, cbuf, (unsigned)t, vB);
    stage(bmB, vB);
    __syncthreads();
    if (!last) spec_issue(gA, nbuf, vA); // in flight under gemm(B)
    gemm(bmB, cI);
    lif(cI, IxB, VB, cntB, gB, nbuf, (unsigned)(t + 1), !last);
  }

  // ---------- write firing rates ----------
  out[(size_t)(gA * 32 + orow) * N_NEU + n0 + ocol] = (float)cntA * 0.015625f;
  out[(size_t)(gB * 32 + orow) * N_NEU + n0 + ocol] = (float)cntB * 0.015625f;
}

extern "C" void kernel_launch(void* const* d_in, const int* in_sizes, int n_in,
                              void* d_out, int out_size, void* d_ws, size_t ws_size,
                              hipStream_t stream) {
  (void)in_sizes; (void)n_in; (void)out_size; (void)ws_size;
  const float* ext  = (const float*)d_in[0];
  const float* Win  = (const float*)d_in[1];
  const float* bin  = (const float*)d_in[2];
  const float* adj  = (const float*)d_in[3];
  const float* mask = (const float*)d_in[4];
  unsigned char* ws = (unsigned char*)d_ws;

  _Float16* Wh   = (_Float16*)(ws);
  _Float16* Wl   = (_Float16*)(ws + (size_t)(8u << 20));
  float*    Iext = (float*)   (ws + (size_t)(16u << 20));
  unsigned long long* bmv = (unsigned long long*)(ws + (size_t)(18u << 20));
  float* out = (float*)d_out;

  hipLaunchKernelGGL(k_wsplit, dim3(2048), dim3(256), 0, stream, adj, mask, Wh, Wl, bmv);
  hipLaunchKernelGGL(k_iext,   dim3(128),  dim3(256), 0, stream, ext, Win, bin, Iext);
  hipLaunchKernelGGL(k_fused9, dim3(256),  dim3(1024), 0, stream,
                     Wh, Wl, Iext, bmv, out);
}

// Round 13
// 615.599 us; speedup vs baseline: 1.0545x; 1.0545x over previous
//
#include <hip/hip_runtime.h>
#include <cstdint>
#include <cstddef>

#define N_NEU 2048
#define D_IN  1024
#define T_STEPS 64

typedef _Float16 f16x8 __attribute__((ext_vector_type(8)));
typedef _Float16 f16x4 __attribute__((ext_vector_type(4)));
typedef float    f32x4 __attribute__((ext_vector_type(4)));
typedef unsigned u32x4 __attribute__((ext_vector_type(4)));
typedef unsigned long long u64x2 __attribute__((ext_vector_type(2)));

#define MFMA16(a, b, c) __builtin_amdgcn_mfma_f32_16x16x32_f16((a), (b), (c), 0, 0, 0)

// ---------------- ws layout (bytes) ----------------
// Wh   [2048][2048] f16   @ 0       (8 MB)
// Wl   [2048][2048] f16   @ 8 MB    (8 MB)
// Iext [256][2048]  f32   @ 16 MB   (2 MB)
// bmv  u64[2][256][64]    @ 18 MB   (256 KB)  (tag<<32)|bits: word (row, n/32), bit n%32

// Split W_eff = adj*mask into f16 hi + f16 lo' (w ~= hi + lo'/4096). Zeroes bmv (replay!).
__global__ __launch_bounds__(256) void k_wsplit(const float* __restrict__ adj,
                                                const float* __restrict__ mask,
                                                _Float16* __restrict__ Wh,
                                                _Float16* __restrict__ Wl,
                                                unsigned long long* __restrict__ bmv) {
  const int idx = blockIdx.x * 256 + threadIdx.x;
  if (idx < 2 * 256 * 64) bmv[idx] = 0ull;
  const int total4 = (N_NEU * N_NEU) / 4;
  for (int i = idx; i < total4; i += gridDim.x * 256) {
    float4 a = ((const float4*)adj)[i];
    float4 m = ((const float4*)mask)[i];
    float w0 = a.x * m.x, w1 = a.y * m.y, w2 = a.z * m.z, w3 = a.w * m.w;
    f16x4 h, lo;
    h[0] = (_Float16)w0; lo[0] = (_Float16)((w0 - (float)h[0]) * 4096.0f);
    h[1] = (_Float16)w1; lo[1] = (_Float16)((w1 - (float)h[1]) * 4096.0f);
    h[2] = (_Float16)w2; lo[2] = (_Float16)((w2 - (float)h[2]) * 4096.0f);
    h[3] = (_Float16)w3; lo[3] = (_Float16)((w3 - (float)h[3]) * 4096.0f);
    ((f16x4*)Wh)[i] = h;
    ((f16x4*)Wl)[i] = lo;
  }
}

// I_ext = ext @ W_in^T + b_in, plain fp32. Proven absmax 0.0 (r1/r5-r12).
__global__ __launch_bounds__(256) void k_iext(const float* __restrict__ ext,
                                              const float* __restrict__ Win,
                                              const float* __restrict__ bin,
                                              float* __restrict__ Iext) {
  __shared__ float At[32][68];
  __shared__ float Bt[32][68];
  const int tid = threadIdx.x;
  const int b0 = (blockIdx.x & 3) * 64;
  const int n0 = (blockIdx.x >> 2) * 64;
  const int tx = tid & 15, ty = tid >> 4;
  float acc[4][4] = {};
  for (int kt = 0; kt < D_IN / 32; ++kt) {
    const int k0 = kt * 32;
#pragma unroll
    for (int i = 0; i < 8; ++i) {
      int e = tid + i * 256;
      int kk = e & 31, row = e >> 5;
      At[kk][row] = ext[(size_t)(b0 + row) * D_IN + k0 + kk];
      Bt[kk][row] = Win[(size_t)(n0 + row) * D_IN + k0 + kk];
    }
    __syncthreads();
    for (int kk = 0; kk < 32; ++kk) {
      f32x4 a = *(const f32x4*)&At[kk][ty * 4];
      f32x4 b = *(const f32x4*)&Bt[kk][tx * 4];
#pragma unroll
      for (int i = 0; i < 4; ++i)
#pragma unroll
        for (int j = 0; j < 4; ++j) acc[i][j] += a[i] * b[j];
    }
    __syncthreads();
  }
#pragma unroll
  for (int i = 0; i < 4; ++i)
#pragma unroll
    for (int j = 0; j < 4; ++j)
      Iext[(size_t)(b0 + ty * 4 + i) * N_NEU + n0 + tx * 4 + j] = acc[i][j] + bin[n0 + tx * 4 + j];
}

// Persistent fused LIF kernel, dual-group zero-barrier dataflow (r11 topology) +
// LDS nibble-LUT expand + flat single-sync split-K tree.
// 256 blocks x 512 thr (1/CU). Block (gp 0..3, ns 0..63): groups gA=gp, gB=gp+4 (32 rows)
// x cols ns*32..+32. 8 waves split K (256 each). Wh+Wl resident in VGPRs.
__global__ __launch_bounds__(512, 2) void k_fused10(
    const _Float16* __restrict__ Wh, const _Float16* __restrict__ Wl,
    const float* __restrict__ Iext, unsigned long long* __restrict__ bmv,
    float* __restrict__ out) {
  __shared__ float red[8 * 32 * 32];        // 32 KB flat split-K reduce (8 slabs)
  __shared__ unsigned bmA[32 * 64];         // 8 KB group-A spike bits (swizzled)
  __shared__ unsigned bmB[32 * 64];         // 8 KB group-B spike bits
  __shared__ unsigned long long lut16[16];  // nibble -> 4 f16 (0/1) LUT

  const int tid = threadIdx.x;
  const int lane = tid & 63;
  const int kw = tid >> 6;        // wave id = split-K index 0..7
  const int l15 = lane & 15;
  const int klo = lane >> 4;      // 0..3
  const int sh = klo * 8;
  const int gp = blockIdx.x >> 6; // 0..3
  const int ns = blockIdx.x & 63; // 0..63
  const int n0 = ns * 32;
  const int gA = gp, gB = gp + 4;
  const float inv4096 = 1.0f / 4096.0f;
  const f32x4 z4 = {0.f, 0.f, 0.f, 0.f};

  // nibble LUT: halfword j = (n>>j)&1 ? 0x3C00 : 0  (ordered before first gemm's sync)
  if (tid < 16) {
    unsigned long long e = 0ull;
    if (tid & 1) e |= 0x3C00ull;
    if (tid & 2) e |= 0x3C00ull << 16;
    if (tid & 4) e |= 0x3C00ull << 32;
    if (tid & 8) e |= 0x3C00ull << 48;
    lut16[tid] = e;
  }

  // ---------- per-thread Iext ----------
  float IxA[2], IxB[2];
#pragma unroll
  for (int j = 0; j < 2; ++j) {
    IxA[j] = Iext[(size_t)(gA * 32 + j * 16 + (tid >> 5)) * N_NEU + n0 + (tid & 31)];
    IxB[j] = Iext[(size_t)(gB * 32 + j * 16 + (tid >> 5)) * N_NEU + n0 + (tid & 31)];
  }

  // ---------- resident Wh + Wl fragments ----------
  const _Float16* whb = Wh + (size_t)(n0 + l15) * N_NEU + kw * 256 + klo * 8;
  const _Float16* wlb = Wl + (size_t)(n0 + l15) * N_NEU + kw * 256 + klo * 8;
  f16x8 whf[2][8], wlf[2][8];
#pragma unroll
  for (int nt = 0; nt < 2; ++nt)
#pragma unroll
    for (int kcl = 0; kcl < 8; ++kcl) {
      whf[nt][kcl] = *(const f16x8*)(whb + nt * 16 * N_NEU + kcl * 32);
      wlf[nt][kcl] = *(const f16x8*)(wlb + nt * 16 * N_NEU + kcl * 32);
    }

  float VA[2] = {0.f, 0.f}, VB[2] = {0.f, 0.f};
  unsigned cA[2] = {0u, 0u}, cB[2] = {0u, 0u};
  unsigned long long vA[4], vB[4];

  // speculative one-shot load of group g's 2048-word slab (4 coalesced u64/thread)
  auto spec_issue = [&](int g, int buf, unsigned long long (&v)[4]) {
    const unsigned long long* src = bmv + (size_t)buf * 16384 + (size_t)g * 2048 + tid;
#pragma unroll
    for (int i = 0; i < 4; ++i)
      v[i] = __hip_atomic_load(src + (size_t)i * 512, __ATOMIC_RELAXED, __HIP_MEMORY_SCOPE_AGENT);
  };
  // validate tags; retry only stale words (issued a compute-phase ago -> rare)
  auto check_retry = [&](int g, int buf, unsigned want, unsigned long long (&v)[4]) {
    const unsigned long long* src = bmv + (size_t)buf * 16384 + (size_t)g * 2048 + tid;
    unsigned need = 0u;
#pragma unroll
    for (int i = 0; i < 4; ++i)
      if ((unsigned)(v[i] >> 32) != want) need |= 1u << i;
    while (need) {
      __builtin_amdgcn_s_sleep(1);
#pragma unroll
      for (int i = 0; i < 4; ++i)
        if (need & (1u << i)) {
          v[i] = __hip_atomic_load(src + (size_t)i * 512,
                                   __ATOMIC_RELAXED, __HIP_MEMORY_SCOPE_AGENT);
          if ((unsigned)(v[i] >> 32) == want) need &= ~(1u << i);
        }
    }
  };
  // stage bits into swizzled LDS: word nsw of row r at [r*64 + (nsw ^ ((r&15)<<2))]
  auto stage = [&](unsigned* bm, const unsigned long long (&v)[4]) {
#pragma unroll
    for (int i = 0; i < 4; ++i) {
      const int w = i * 512 + tid, r = w >> 6, nsw = w & 63;
      bm[r * 64 + (nsw ^ ((r & 15) << 2))] = (unsigned)v[i];
    }
  };
  // nibble-LUT expand: 8 bits -> 8 f16 via 2 ds_read_b64
  auto exp8 = [&](unsigned b) -> f16x8 {
    u64x2 t;
    t[0] = lut16[b & 15u];
    t[1] = lut16[(b >> 4) & 15u];
    return __builtin_bit_cast(f16x8, t);
  };
  // K-loop + flat 8-slab split-K tree (ONE sync) -> cI[2]
  auto gemm = [&](const unsigned* bm, float (&cI)[2]) {
    f32x4 acch[2][2], accl[2][2];
#pragma unroll
    for (int mt = 0; mt < 2; ++mt)
#pragma unroll
      for (int nt = 0; nt < 2; ++nt) { acch[mt][nt] = z4; accl[mt][nt] = z4; }
#pragma unroll
    for (int mt = 0; mt < 2; ++mt) {
      const int row = mt * 16 + l15;
      const int swz = l15 << 2;
      const u32x4 q0 = *(const u32x4*)&bm[row * 64 + ((kw * 8) ^ swz)];
      const u32x4 q1 = *(const u32x4*)&bm[row * 64 + (((kw * 8) | 4) ^ swz)];
#pragma unroll
      for (int kcl = 0; kcl < 8; ++kcl) {
        const unsigned word = (kcl < 4) ? q0[kcl] : q1[kcl - 4];
        const f16x8 a = exp8((word >> sh) & 0xFFu);
        acch[mt][0] = MFMA16(a, whf[0][kcl], acch[mt][0]);
        accl[mt][0] = MFMA16(a, wlf[0][kcl], accl[mt][0]);
        acch[mt][1] = MFMA16(a, whf[1][kcl], acch[mt][1]);
        accl[mt][1] = MFMA16(a, wlf[1][kcl], accl[mt][1]);
      }
    }
    f32x4 cb[2][2];
#pragma unroll
    for (int mt = 0; mt < 2; ++mt)
#pragma unroll
      for (int nt = 0; nt < 2; ++nt) cb[mt][nt] = acch[mt][nt] + accl[mt][nt] * inv4096;
    // flat tree: every wave stores its partial into slab kw; one sync; 8-way sum
    const int cbn = lane & 15, rq = (lane >> 4) << 2;
#pragma unroll
    for (int mt = 0; mt < 2; ++mt)
#pragma unroll
      for (int nt = 0; nt < 2; ++nt) {
        const int col = nt * 16 + cbn;
        const int r0 = (mt * 16 + rq) ^ ((col & 7) << 2);
        *(f32x4*)(red + (kw * 32 + col) * 32 + r0) = cb[mt][nt];
      }
    __syncthreads();
#pragma unroll
    for (int j = 0; j < 2; ++j) {
      const int o = j * 512 + tid;
      const int row = o >> 5, col = o & 31;
      const int rs = row ^ ((col & 7) << 2);
      float s = 0.0f;
#pragma unroll
      for (int p = 0; p < 8; ++p) s += red[(p * 32 + col) * 32 + rs];
      cI[j] = s;
    }
  };
  // LIF + tagged spike stores (tag and bits in ONE u64: single-copy-atomic)
  auto lif = [&](const float (&cI)[2], const float (&Ix)[2], float (&V)[2],
                 unsigned (&cnt)[2], int g, int nbuf, unsigned tag, bool dostore) {
#pragma unroll
    for (int j = 0; j < 2; ++j) {
      float I = cI[j] + Ix[j];
      float v = 0.9f * V[j] + I;
      bool sp = (v - 1.0f) >= 0.0f;
      V[j] = sp ? 0.0f : v;
      cnt[j] += sp ? 1u : 0u;
      if (dostore) {
        unsigned long long ba = __ballot(sp);
        const int rowf = g * 32 + j * 16 + kw * 2;  // lanes 0-31: rowf, 32-63: rowf+1
        const unsigned long long tg = ((unsigned long long)tag) << 32;
        if (lane == 0)
          __hip_atomic_store(bmv + (size_t)nbuf * 16384 + (size_t)rowf * 64 + ns,
                             tg | (unsigned)ba, __ATOMIC_RELAXED, __HIP_MEMORY_SCOPE_AGENT);
        else if (lane == 32)
          __hip_atomic_store(bmv + (size_t)nbuf * 16384 + (size_t)(rowf + 1) * 64 + ns,
                             tg | (unsigned)(ba >> 32), __ATOMIC_RELAXED, __HIP_MEMORY_SCOPE_AGENT);
      }
    }
  };

  // ---------- t = 0: Iext-only LIF; spikes tagged 1 -> buf 1; prefetch A ----------
  {
    const float cz[2] = {0.f, 0.f};
    lif(cz, IxA, VA, cA, gA, 1, 1u, true);
    lif(cz, IxB, VB, cB, gB, 1, 1u, true);
    spec_issue(gA, 1, vA);
  }

  for (int t = 1; t < T_STEPS; ++t) {
    const int cbuf = t & 1, nbuf = (t + 1) & 1;
    const bool last = (t == T_STEPS - 1);
    float cI[2];

    // ---- phase A ----
    spec_issue(gB, cbuf, vB);            // widest window: in flight under stage+gemm(A)
    check_retry(gA, cbuf, (unsigned)t, vA);
    stage(bmA, vA);
    __syncthreads();
    gemm(bmA, cI);
    lif(cI, IxA, VA, cA, gA, nbuf, (unsigned)(t + 1), !last);

    // ---- phase B ----
    check_retry(gB, cbuf, (unsigned)t, vB);
    stage(bmB, vB);
    __syncthreads();
    if (!last) spec_issue(gA, nbuf, vA); // in flight under gemm(B)
    gemm(bmB, cI);
    lif(cI, IxB, VB, cB, gB, nbuf, (unsigned)(t + 1), !last);
  }

  // ---------- write firing rates ----------
#pragma unroll
  for (int j = 0; j < 2; ++j) {
    const int rA = gA * 32 + j * 16 + (tid >> 5);
    const int rB = gB * 32 + j * 16 + (tid >> 5);
    out[(size_t)rA * N_NEU + n0 + (tid & 31)] = (float)cA[j] * 0.015625f;
    out[(size_t)rB * N_NEU + n0 + (tid & 31)] = (float)cB[j] * 0.015625f;
  }
}

extern "C" void kernel_launch(void* const* d_in, const int* in_sizes, int n_in,
                              void* d_out, int out_size, void* d_ws, size_t ws_size,
                              hipStream_t stream) {
  (void)in_sizes; (void)n_in; (void)out_size; (void)ws_size;
  const float* ext  = (const float*)d_in[0];
  const float* Win  = (const float*)d_in[1];
  const float* bin  = (const float*)d_in[2];
  const float* adj  = (const float*)d_in[3];
  const float* mask = (const float*)d_in[4];
  unsigned char* ws = (unsigned char*)d_ws;

  _Float16* Wh   = (_Float16*)(ws);
  _Float16* Wl   = (_Float16*)(ws + (size_t)(8u << 20));
  float*    Iext = (float*)   (ws + (size_t)(16u << 20));
  unsigned long long* bmv = (unsigned long long*)(ws + (size_t)(18u << 20));
  float* out = (float*)d_out;

  hipLaunchKernelGGL(k_wsplit, dim3(2048), dim3(256), 0, stream, adj, mask, Wh, Wl, bmv);
  hipLaunchKernelGGL(k_iext,   dim3(128),  dim3(256), 0, stream, ext, Win, bin, Iext);
  hipLaunchKernelGGL(k_fused10, dim3(256), dim3(512), 0, stream,
                     Wh, Wl, Iext, bmv, out);
}

// Round 14
// 443.224 us; speedup vs baseline: 1.4646x; 1.3889x over previous
//
#include <hip/hip_runtime.h>
#include <cstdint>
#include <cstddef>

#define N_NEU 2048
#define D_IN  1024
#define T_STEPS 64

typedef _Float16 f16x8 __attribute__((ext_vector_type(8)));
typedef _Float16 f16x4 __attribute__((ext_vector_type(4)));
typedef float    f32x4 __attribute__((ext_vector_type(4)));
typedef unsigned u32x4 __attribute__((ext_vector_type(4)));

#define MFMA16(a, b, c) __builtin_amdgcn_mfma_f32_16x16x32_f16((a), (b), (c), 0, 0, 0)

// ---------------- ws layout (bytes) ----------------
// Wh   [2048][2048] f16   @ 0       (8 MB)
// Wl   [2048][2048] f16   @ 8 MB    (8 MB)
// Iext [256][2048]  f32   @ 16 MB   (2 MB)
// bmv  u64[2][256][64]    @ 18 MB   (256 KB)  (tag<<32)|bits: word (row, n/32), bit n%32

// 8 bits -> 8 f16 (0.0/1.0) via multiply-spread: 4 VALU/word, no cndmask chains, no LDS.
__device__ inline f16x8 expand8(unsigned b) {
  u32x4 t;
#pragma unroll
  for (int i = 0; i < 4; ++i) {
    unsigned m = (b >> (2 * i)) & 3u;              // v_bfe_u32
    unsigned s = (m | (m << 15)) & 0x00010001u;    // v_lshl_or + v_and
    t[i] = s * 0x3C00u;                            // v_mul_u32_u24
  }
  return __builtin_bit_cast(f16x8, t);
}

// Split W_eff = adj*mask into f16 hi + f16 lo' (w ~= hi + lo'/4096). Zeroes bmv (replay!).
__global__ __launch_bounds__(256) void k_wsplit(const float* __restrict__ adj,
                                                const float* __restrict__ mask,
                                                _Float16* __restrict__ Wh,
                                                _Float16* __restrict__ Wl,
                                                unsigned long long* __restrict__ bmv) {
  const int idx = blockIdx.x * 256 + threadIdx.x;
  if (idx < 2 * 256 * 64) bmv[idx] = 0ull;
  const int total4 = (N_NEU * N_NEU) / 4;
  for (int i = idx; i < total4; i += gridDim.x * 256) {
    float4 a = ((const float4*)adj)[i];
    float4 m = ((const float4*)mask)[i];
    float w0 = a.x * m.x, w1 = a.y * m.y, w2 = a.z * m.z, w3 = a.w * m.w;
    f16x4 h, lo;
    h[0] = (_Float16)w0; lo[0] = (_Float16)((w0 - (float)h[0]) * 4096.0f);
    h[1] = (_Float16)w1; lo[1] = (_Float16)((w1 - (float)h[1]) * 4096.0f);
    h[2] = (_Float16)w2; lo[2] = (_Float16)((w2 - (float)h[2]) * 4096.0f);
    h[3] = (_Float16)w3; lo[3] = (_Float16)((w3 - (float)h[3]) * 4096.0f);
    ((f16x4*)Wh)[i] = h;
    ((f16x4*)Wl)[i] = lo;
  }
}

// I_ext = ext @ W_in^T + b_in, plain fp32. Proven absmax 0.0 (r1/r5-r13).
__global__ __launch_bounds__(256) void k_iext(const float* __restrict__ ext,
                                              const float* __restrict__ Win,
                                              const float* __restrict__ bin,
                                              float* __restrict__ Iext) {
  __shared__ float At[32][68];
  __shared__ float Bt[32][68];
  const int tid = threadIdx.x;
  const int b0 = (blockIdx.x & 3) * 64;
  const int n0 = (blockIdx.x >> 2) * 64;
  const int tx = tid & 15, ty = tid >> 4;
  float acc[4][4] = {};
  for (int kt = 0; kt < D_IN / 32; ++kt) {
    const int k0 = kt * 32;
#pragma unroll
    for (int i = 0; i < 8; ++i) {
      int e = tid + i * 256;
      int kk = e & 31, row = e >> 5;
      At[kk][row] = ext[(size_t)(b0 + row) * D_IN + k0 + kk];
      Bt[kk][row] = Win[(size_t)(n0 + row) * D_IN + k0 + kk];
    }
    __syncthreads();
    for (int kk = 0; kk < 32; ++kk) {
      f32x4 a = *(const f32x4*)&At[kk][ty * 4];
      f32x4 b = *(const f32x4*)&Bt[kk][tx * 4];
#pragma unroll
      for (int i = 0; i < 4; ++i)
#pragma unroll
        for (int j = 0; j < 4; ++j) acc[i][j] += a[i] * b[j];
    }
    __syncthreads();
  }
#pragma unroll
  for (int i = 0; i < 4; ++i)
#pragma unroll
    for (int j = 0; j < 4; ++j)
      Iext[(size_t)(b0 + ty * 4 + i) * N_NEU + n0 + tx * 4 + j] = acc[i][j] + bin[n0 + tx * 4 + j];
}

// Persistent fused LIF kernel, dual-group zero-barrier dataflow (r11 topology verbatim)
// + flat single-sync split-K tree + multiply-spread expand.
// 256 blocks x 512 thr (1/CU). Block (gp 0..3, ns 0..63): groups gA=gp, gB=gp+4 (32 rows)
// x cols ns*32..+32. 8 waves split K (256 each). Wh+Wl resident in VGPRs.
__global__ __launch_bounds__(512, 2) void k_fused11(
    const _Float16* __restrict__ Wh, const _Float16* __restrict__ Wl,
    const float* __restrict__ Iext, unsigned long long* __restrict__ bmv,
    float* __restrict__ out) {
  __shared__ float red[8 * 32 * 32];   // 32 KB flat split-K reduce (8 slabs)
  __shared__ unsigned bmA[32 * 64];    // 8 KB group-A spike bits (swizzled)
  __shared__ unsigned bmB[32 * 64];    // 8 KB group-B spike bits

  const int tid = threadIdx.x;
  const int lane = tid & 63;
  const int kw = tid >> 6;        // wave id = split-K index 0..7
  const int l15 = lane & 15;
  const int klo = lane >> 4;      // 0..3
  const int sh = klo * 8;
  const int gp = blockIdx.x >> 6; // 0..3
  const int ns = blockIdx.x & 63; // 0..63
  const int n0 = ns * 32;
  const int gA = gp, gB = gp + 4;
  const float inv4096 = 1.0f / 4096.0f;
  const f32x4 z4 = {0.f, 0.f, 0.f, 0.f};

  // ---------- per-thread Iext ----------
  float IxA[2], IxB[2];
#pragma unroll
  for (int j = 0; j < 2; ++j) {
    IxA[j] = Iext[(size_t)(gA * 32 + j * 16 + (tid >> 5)) * N_NEU + n0 + (tid & 31)];
    IxB[j] = Iext[(size_t)(gB * 32 + j * 16 + (tid >> 5)) * N_NEU + n0 + (tid & 31)];
  }

  // ---------- resident Wh + Wl fragments ----------
  const _Float16* whb = Wh + (size_t)(n0 + l15) * N_NEU + kw * 256 + klo * 8;
  const _Float16* wlb = Wl + (size_t)(n0 + l15) * N_NEU + kw * 256 + klo * 8;
  f16x8 whf[2][8], wlf[2][8];
#pragma unroll
  for (int nt = 0; nt < 2; ++nt)
#pragma unroll
    for (int kcl = 0; kcl < 8; ++kcl) {
      whf[nt][kcl] = *(const f16x8*)(whb + nt * 16 * N_NEU + kcl * 32);
      wlf[nt][kcl] = *(const f16x8*)(wlb + nt * 16 * N_NEU + kcl * 32);
    }

  float VA[2] = {0.f, 0.f}, VB[2] = {0.f, 0.f};
  unsigned cA[2] = {0u, 0u}, cB[2] = {0u, 0u};
  unsigned long long vA[4], vB[4];

  // speculative one-shot load of group g's 2048-word slab (4 coalesced u64/thread)
  auto spec_issue = [&](int g, int buf, unsigned long long (&v)[4]) {
    const unsigned long long* src = bmv + (size_t)buf * 16384 + (size_t)g * 2048 + tid;
#pragma unroll
    for (int i = 0; i < 4; ++i)
      v[i] = __hip_atomic_load(src + (size_t)i * 512, __ATOMIC_RELAXED, __HIP_MEMORY_SCOPE_AGENT);
  };
  // validate tags; retry only stale words (rare: issued a compute-phase ago)
  auto check_retry = [&](int g, int buf, unsigned want, unsigned long long (&v)[4]) {
    const unsigned long long* src = bmv + (size_t)buf * 16384 + (size_t)g * 2048 + tid;
    unsigned need = 0u;
#pragma unroll
    for (int i = 0; i < 4; ++i)
      if ((unsigned)(v[i] >> 32) != want) need |= 1u << i;
    while (need) {
      __builtin_amdgcn_s_sleep(2);
#pragma unroll
      for (int i = 0; i < 4; ++i)
        if (need & (1u << i)) {
          v[i] = __hip_atomic_load(src + (size_t)i * 512,
                                   __ATOMIC_RELAXED, __HIP_MEMORY_SCOPE_AGENT);
          if ((unsigned)(v[i] >> 32) == want) need &= ~(1u << i);
        }
    }
  };
  // stage bits into swizzled LDS: word nsw of row r at [r*64 + (nsw ^ ((r&15)<<2))]
  auto stage = [&](unsigned* bm, const unsigned long long (&v)[4]) {
#pragma unroll
    for (int i = 0; i < 4; ++i) {
      const int w = i * 512 + tid, r = w >> 6, nsw = w & 63;
      bm[r * 64 + (nsw ^ ((r & 15) << 2))] = (unsigned)v[i];
    }
  };
  // K-loop + flat 8-slab split-K tree (ONE sync) -> cI[2]
  auto gemm = [&](const unsigned* bm, float (&cI)[2]) {
    f32x4 acch[2][2], accl[2][2];
#pragma unroll
    for (int mt = 0; mt < 2; ++mt)
#pragma unroll
      for (int nt = 0; nt < 2; ++nt) { acch[mt][nt] = z4; accl[mt][nt] = z4; }
#pragma unroll
    for (int mt = 0; mt < 2; ++mt) {
      const int row = mt * 16 + l15;
      const int swz = l15 << 2;
      const u32x4 q0 = *(const u32x4*)&bm[row * 64 + ((kw * 8) ^ swz)];
      const u32x4 q1 = *(const u32x4*)&bm[row * 64 + (((kw * 8) | 4) ^ swz)];
#pragma unroll
      for (int kcl = 0; kcl < 8; ++kcl) {
        const unsigned word = (kcl < 4) ? q0[kcl] : q1[kcl - 4];
        const f16x8 a = expand8((word >> sh) & 0xFFu);
        acch[mt][0] = MFMA16(a, whf[0][kcl], acch[mt][0]);
        accl[mt][0] = MFMA16(a, wlf[0][kcl], accl[mt][0]);
        acch[mt][1] = MFMA16(a, whf[1][kcl], acch[mt][1]);
        accl[mt][1] = MFMA16(a, wlf[1][kcl], accl[mt][1]);
      }
    }
    f32x4 cb[2][2];
#pragma unroll
    for (int mt = 0; mt < 2; ++mt)
#pragma unroll
      for (int nt = 0; nt < 2; ++nt) cb[mt][nt] = acch[mt][nt] + accl[mt][nt] * inv4096;
    // flat tree: every wave stores its partial into slab kw; one sync; 8-way sum
    const int cbn = lane & 15, rq = (lane >> 4) << 2;
#pragma unroll
    for (int mt = 0; mt < 2; ++mt)
#pragma unroll
      for (int nt = 0; nt < 2; ++nt) {
        const int col = nt * 16 + cbn;
        const int r0 = (mt * 16 + rq) ^ ((col & 7) << 2);
        *(f32x4*)(red + (kw * 32 + col) * 32 + r0) = cb[mt][nt];
      }
    __syncthreads();
#pragma unroll
    for (int j = 0; j < 2; ++j) {
      const int o = j * 512 + tid;
      const int row = o >> 5, col = o & 31;
      const int rs = row ^ ((col & 7) << 2);
      float s = 0.0f;
#pragma unroll
      for (int p = 0; p < 8; ++p) s += red[(p * 32 + col) * 32 + rs];
      cI[j] = s;
    }
  };
  // LIF + tagged spike stores (tag and bits in ONE u64: single-copy-atomic)
  auto lif = [&](const float (&cI)[2], const float (&Ix)[2], float (&V)[2],
                 unsigned (&cnt)[2], int g, int nbuf, unsigned tag, bool dostore) {
#pragma unroll
    for (int j = 0; j < 2; ++j) {
      float I = cI[j] + Ix[j];
      float v = 0.9f * V[j] + I;
      bool sp = (v - 1.0f) >= 0.0f;
      V[j] = sp ? 0.0f : v;
      cnt[j] += sp ? 1u : 0u;
      if (dostore) {
        unsigned long long ba = __ballot(sp);
        const int rowf = g * 32 + j * 16 + kw * 2;  // lanes 0-31: rowf, 32-63: rowf+1
        const unsigned long long tg = ((unsigned long long)tag) << 32;
        if (lane == 0)
          __hip_atomic_store(bmv + (size_t)nbuf * 16384 + (size_t)rowf * 64 + ns,
                             tg | (unsigned)ba, __ATOMIC_RELAXED, __HIP_MEMORY_SCOPE_AGENT);
        else if (lane == 32)
          __hip_atomic_store(bmv + (size_t)nbuf * 16384 + (size_t)(rowf + 1) * 64 + ns,
                             tg | (unsigned)(ba >> 32), __ATOMIC_RELAXED, __HIP_MEMORY_SCOPE_AGENT);
      }
    }
  };

  // ---------- t = 0: Iext-only LIF; spikes tagged 1 -> buf 1; prefetch A ----------
  {
    const float cz[2] = {0.f, 0.f};
    lif(cz, IxA, VA, cA, gA, 1, 1u, true);
    lif(cz, IxB, VB, cB, gB, 1, 1u, true);
    spec_issue(gA, 1, vA);
  }

  for (int t = 1; t < T_STEPS; ++t) {
    const int cbuf = t & 1, nbuf = (t + 1) & 1;
    const bool last = (t == T_STEPS - 1);
    float cI[2];

    // ---- phase A ----
    check_retry(gA, cbuf, (unsigned)t, vA);
    stage(bmA, vA);
    __syncthreads();
    spec_issue(gB, cbuf, vB);            // in flight under gemm(A)  [r11 placement]
    gemm(bmA, cI);
    lif(cI, IxA, VA, cA, gA, nbuf, (unsigned)(t + 1), !last);

    // ---- phase B ----
    check_retry(gB, cbuf, (unsigned)t, vB);
    stage(bmB, vB);
    __syncthreads();
    if (!last) spec_issue(gA, nbuf, vA); // in flight under gemm(B)  [r11 placement]
    gemm(bmB, cI);
    lif(cI, IxB, VB, cB, gB, nbuf, (unsigned)(t + 1), !last);
  }

  // ---------- write firing rates ----------
#pragma unroll
  for (int j = 0; j < 2; ++j) {
    const int rA = gA * 32 + j * 16 + (tid >> 5);
    const int rB = gB * 32 + j * 16 + (tid >> 5);
    out[(size_t)rA * N_NEU + n0 + (tid & 31)] = (float)cA[j] * 0.015625f;
    out[(size_t)rB * N_NEU + n0 + (tid & 31)] = (float)cB[j] * 0.015625f;
  }
}

extern "C" void kernel_launch(void* const* d_in, const int* in_sizes, int n_in,
                              void* d_out, int out_size, void* d_ws, size_t ws_size,
                              hipStream_t stream) {
  (void)in_sizes; (void)n_in; (void)out_size; (void)ws_size;
  const float* ext  = (const float*)d_in[0];
  const float* Win  = (const float*)d_in[1];
  const float* bin  = (const float*)d_in[2];
  const float* adj  = (const float*)d_in[3];
  const float* mask = (const float*)d_in[4];
  unsigned char* ws = (unsigned char*)d_ws;

  _Float16* Wh   = (_Float16*)(ws);
  _Float16* Wl   = (_Float16*)(ws + (size_t)(8u << 20));
  float*    Iext = (float*)   (ws + (size_t)(16u << 20));
  unsigned long long* bmv = (unsigned long long*)(ws + (size_t)(18u << 20));
  float* out = (float*)d_out;

  hipLaunchKernelGGL(k_wsplit, dim3(2048), dim3(256), 0, stream, adj, mask, Wh, Wl, bmv);
  hipLaunchKernelGGL(k_iext,   dim3(128),  dim3(256), 0, stream, ext, Win, bin, Iext);
  hipLaunchKernelGGL(k_fused11, dim3(256), dim3(512), 0, stream,
                     Wh, Wl, Iext, bmv, out);
}

// Round 15
// 441.089 us; speedup vs baseline: 1.4717x; 1.0048x over previous
//
#include <hip/hip_runtime.h>
#include <cstdint>
#include <cstddef>

#define N_NEU 2048
#define D_IN  1024
#define T_STEPS 64

typedef _Float16 f16x8 __attribute__((ext_vector_type(8)));
typedef _Float16 f16x4 __attribute__((ext_vector_type(4)));
typedef float    f32x4 __attribute__((ext_vector_type(4)));
typedef unsigned u32x4 __attribute__((ext_vector_type(4)));

#define MFMA16(a, b, c) __builtin_amdgcn_mfma_f32_16x16x32_f16((a), (b), (c), 0, 0, 0)

// ---------------- ws layout (bytes) ----------------
// Wh   [2048][2048] f16   @ 0       (8 MB)
// Wl   [2048][2048] f16   @ 8 MB    (8 MB)
// Iext [256][2048]  f32   @ 16 MB   (2 MB)
// bmv  u64[2][256][64]    @ 18 MB   (256 KB)  (tag<<32)|bits: word (row, n/32), bit n%32

// 8 bits -> 8 f16 (0.0/1.0) via multiply-spread: 4 VALU/word.
__device__ inline f16x8 expand8(unsigned b) {
  u32x4 t;
#pragma unroll
  for (int i = 0; i < 4; ++i) {
    unsigned m = (b >> (2 * i)) & 3u;
    unsigned s = (m | (m << 15)) & 0x00010001u;
    t[i] = s * 0x3C00u;
  }
  return __builtin_bit_cast(f16x8, t);
}

// Split W_eff = adj*mask into f16 hi + f16 lo' (w ~= hi + lo'/4096). Zeroes bmv (replay!).
__global__ __launch_bounds__(256) void k_wsplit(const float* __restrict__ adj,
                                                const float* __restrict__ mask,
                                                _Float16* __restrict__ Wh,
                                                _Float16* __restrict__ Wl,
                                                unsigned long long* __restrict__ bmv) {
  const int idx = blockIdx.x * 256 + threadIdx.x;
  if (idx < 2 * 256 * 64) bmv[idx] = 0ull;
  const int total4 = (N_NEU * N_NEU) / 4;
  for (int i = idx; i < total4; i += gridDim.x * 256) {
    float4 a = ((const float4*)adj)[i];
    float4 m = ((const float4*)mask)[i];
    float w0 = a.x * m.x, w1 = a.y * m.y, w2 = a.z * m.z, w3 = a.w * m.w;
    f16x4 h, lo;
    h[0] = (_Float16)w0; lo[0] = (_Float16)((w0 - (float)h[0]) * 4096.0f);
    h[1] = (_Float16)w1; lo[1] = (_Float16)((w1 - (float)h[1]) * 4096.0f);
    h[2] = (_Float16)w2; lo[2] = (_Float16)((w2 - (float)h[2]) * 4096.0f);
    h[3] = (_Float16)w3; lo[3] = (_Float16)((w3 - (float)h[3]) * 4096.0f);
    ((f16x4*)Wh)[i] = h;
    ((f16x4*)Wl)[i] = lo;
  }
}

// I_ext = ext @ W_in^T + b_in, plain fp32. Proven absmax 0.0 (r1/r5-r14).
__global__ __launch_bounds__(256) void k_iext(const float* __restrict__ ext,
                                              const float* __restrict__ Win,
                                              const float* __restrict__ bin,
                                              float* __restrict__ Iext) {
  __shared__ float At[32][68];
  __shared__ float Bt[32][68];
  const int tid = threadIdx.x;
  const int b0 = (blockIdx.x & 3) * 64;
  const int n0 = (blockIdx.x >> 2) * 64;
  const int tx = tid & 15, ty = tid >> 4;
  float acc[4][4] = {};
  for (int kt = 0; kt < D_IN / 32; ++kt) {
    const int k0 = kt * 32;
#pragma unroll
    for (int i = 0; i < 8; ++i) {
      int e = tid + i * 256;
      int kk = e & 31, row = e >> 5;
      At[kk][row] = ext[(size_t)(b0 + row) * D_IN + k0 + kk];
      Bt[kk][row] = Win[(size_t)(n0 + row) * D_IN + k0 + kk];
    }
    __syncthreads();
    for (int kk = 0; kk < 32; ++kk) {
      f32x4 a = *(const f32x4*)&At[kk][ty * 4];
      f32x4 b = *(const f32x4*)&Bt[kk][tx * 4];
#pragma unroll
      for (int i = 0; i < 4; ++i)
#pragma unroll
        for (int j = 0; j < 4; ++j) acc[i][j] += a[i] * b[j];
    }
    __syncthreads();
  }
#pragma unroll
  for (int i = 0; i < 4; ++i)
#pragma unroll
    for (int j = 0; j < 4; ++j)
      Iext[(size_t)(b0 + ty * 4 + i) * N_NEU + n0 + tx * 4 + j] = acc[i][j] + bin[n0 + tx * 4 + j];
}

// Persistent fused LIF kernel: 4-group deep-pipelined zero-barrier dataflow.
// 256 blocks x 512 thr (1/CU). Block (gp 0..3, ns 0..63): batch rows gp*64..+64 as 4
// groups of 16, cols ns*32..+32. 8 waves split K (256 each); Wh+Wl resident in VGPRs.
// Group data produced 4 phases before consumption; prefetch 2 phases ahead. Each thread
// owns ONE output element per group (orow=tid>>5, ocol=tid&31).
__global__ __launch_bounds__(512, 2) void k_fused12(
    const _Float16* __restrict__ Wh, const _Float16* __restrict__ Wl,
    const float* __restrict__ Iext, unsigned long long* __restrict__ bmv,
    float* __restrict__ out) {
  __shared__ float red[8 * 32 * 20];   // 20.5 KB: [wave][col][row(16)+pad4]
  __shared__ unsigned bm[16 * 68];     // 4.25 KB: [row][word], stride 68 (aligned+spread)

  const int tid = threadIdx.x;
  const int lane = tid & 63;
  const int kw = tid >> 6;        // wave id = split-K index 0..7
  const int l15 = lane & 15;
  const int klo = lane >> 4;      // 0..3
  const int sh = klo * 8;
  const int gp = blockIdx.x >> 6; // clique 0..3 (rows gp*64..+64)
  const int ns = blockIdx.x & 63;
  const int n0 = ns * 32;
  const int orow = tid >> 5;      // 0..15
  const int ocol = tid & 31;
  const float inv4096 = 1.0f / 4096.0f;
  const f32x4 z4 = {0.f, 0.f, 0.f, 0.f};

  // ---------- per-thread Iext, one scalar per group ----------
  const float Ix0 = Iext[(size_t)(gp * 64 +  0 + orow) * N_NEU + n0 + ocol];
  const float Ix1 = Iext[(size_t)(gp * 64 + 16 + orow) * N_NEU + n0 + ocol];
  const float Ix2 = Iext[(size_t)(gp * 64 + 32 + orow) * N_NEU + n0 + ocol];
  const float Ix3 = Iext[(size_t)(gp * 64 + 48 + orow) * N_NEU + n0 + ocol];

  // ---------- resident Wh + Wl fragments (r11-proven layout) ----------
  const _Float16* whb = Wh + (size_t)(n0 + l15) * N_NEU + kw * 256 + klo * 8;
  const _Float16* wlb = Wl + (size_t)(n0 + l15) * N_NEU + kw * 256 + klo * 8;
  f16x8 whf[2][8], wlf[2][8];
#pragma unroll
  for (int nt = 0; nt < 2; ++nt)
#pragma unroll
    for (int kcl = 0; kcl < 8; ++kcl) {
      whf[nt][kcl] = *(const f16x8*)(whb + nt * 16 * N_NEU + kcl * 32);
      wlf[nt][kcl] = *(const f16x8*)(wlb + nt * 16 * N_NEU + kcl * 32);
    }

  float V0 = 0.f, V1 = 0.f, V2 = 0.f, V3 = 0.f;        // scalar state, no dyn indexing
  unsigned c0 = 0u, c1 = 0u, c2 = 0u, c3 = 0u;
  unsigned long long vqE[2], vqO[2];                   // prefetch regs, even/odd phases

  // issue: speculative coalesced load of group gI's 16-row slab for step tI
  auto issue = [&](int tI, int gI, unsigned long long (&v)[2]) {
    const unsigned long long* src = bmv + (size_t)(tI & 1) * 16384
        + (size_t)(gp * 64 + gI * 16) * 64 + tid;
    v[0] = __hip_atomic_load(src, __ATOMIC_RELAXED, __HIP_MEMORY_SCOPE_AGENT);
    v[1] = __hip_atomic_load(src + 512, __ATOMIC_RELAXED, __HIP_MEMORY_SCOPE_AGENT);
  };
  // check: validate tags == tC; retry only stale words
  auto check = [&](int tC, int gC, unsigned long long (&v)[2]) {
    const unsigned long long* src = bmv + (size_t)(tC & 1) * 16384
        + (size_t)(gp * 64 + gC * 16) * 64 + tid;
    const unsigned want = (unsigned)tC;
    unsigned need = 0u;
    if ((unsigned)(v[0] >> 32) != want) need |= 1u;
    if ((unsigned)(v[1] >> 32) != want) need |= 2u;
    while (need) {
      __builtin_amdgcn_s_sleep(1);
      if (need & 1u) {
        v[0] = __hip_atomic_load(src, __ATOMIC_RELAXED, __HIP_MEMORY_SCOPE_AGENT);
        if ((unsigned)(v[0] >> 32) == want) need &= ~1u;
      }
      if (need & 2u) {
        v[1] = __hip_atomic_load(src + 512, __ATOMIC_RELAXED, __HIP_MEMORY_SCOPE_AGENT);
        if ((unsigned)(v[1] >> 32) == want) need &= ~2u;
      }
    }
  };
  // stage bits into LDS [row][word], stride 68
  auto stage = [&](const unsigned long long (&v)[2]) {
    bm[(tid >> 6) * 68 + (tid & 63)] = (unsigned)v[0];
    bm[((tid + 512) >> 6) * 68 + (tid & 63)] = (unsigned)v[1];
  };
  // one phase's GEMM: 16 rows x 32 cols x K2048 (8-way split) -> scalar output
  auto gemm_phase = [&](float& cI) {
    f32x4 acch[2], accl[2];
    acch[0] = z4; acch[1] = z4; accl[0] = z4; accl[1] = z4;
    const u32x4 q0 = *(const u32x4*)&bm[l15 * 68 + kw * 8];
    const u32x4 q1 = *(const u32x4*)&bm[l15 * 68 + kw * 8 + 4];
#pragma unroll
    for (int kcl = 0; kcl < 8; ++kcl) {
      const unsigned word = (kcl < 4) ? q0[kcl] : q1[kcl - 4];
      const f16x8 a = expand8((word >> sh) & 0xFFu);
      acch[0] = MFMA16(a, whf[0][kcl], acch[0]);
      accl[0] = MFMA16(a, wlf[0][kcl], accl[0]);
      acch[1] = MFMA16(a, whf[1][kcl], acch[1]);
      accl[1] = MFMA16(a, wlf[1][kcl], accl[1]);
    }
    const int rq = (lane >> 4) << 2;   // C rows rq..rq+3 (m89 layout), col = nt*16+l15
#pragma unroll
    for (int nt = 0; nt < 2; ++nt) {
      f32x4 cb = acch[nt] + accl[nt] * inv4096;
      *(f32x4*)&red[(kw * 32 + nt * 16 + l15) * 20 + rq] = cb;
    }
    __syncthreads();
    float s = 0.0f;
#pragma unroll
    for (int p = 0; p < 8; ++p) s += red[(p * 32 + ocol) * 20 + orow];
    cI = s;
  };
  // LIF + tagged spike store (tag tL+1, buf (tL+1)&1)
  auto lifp = [&](float cI, float Ixg, float& Vg, unsigned& cg, int tL, int gL) {
    float I = cI + Ixg;
    float vm = 0.9f * Vg + I;
    bool sp = (vm - 1.0f) >= 0.0f;
    Vg = sp ? 0.0f : vm;
    cg += sp ? 1u : 0u;
    if (tL < T_STEPS - 1) {
      unsigned long long ba = __ballot(sp);
      const int rowf = gp * 64 + gL * 16 + kw * 2;  // lanes 0-31: rowf, 32-63: rowf+1
      const unsigned long long tg = ((unsigned long long)(unsigned)(tL + 1)) << 32;
      unsigned long long* dst = bmv + (size_t)((tL + 1) & 1) * 16384;
      if (lane == 0)
        __hip_atomic_store(dst + (size_t)rowf * 64 + ns, tg | (unsigned)ba,
                           __ATOMIC_RELAXED, __HIP_MEMORY_SCOPE_AGENT);
      else if (lane == 32)
        __hip_atomic_store(dst + (size_t)(rowf + 1) * 64 + ns, tg | (unsigned)(ba >> 32),
                           __ATOMIC_RELAXED, __HIP_MEMORY_SCOPE_AGENT);
    }
  };
  // full phase: check -> stage -> sync -> prefetch(P+2) -> gemm -> LIF
  auto phase = [&](int tP, int gP, float Ixg, float& Vg, unsigned& cg,
                   unsigned long long (&v)[2], int tI, int gI, bool doIss) {
    check(tP, gP, v);
    stage(v);
    __syncthreads();                  // bm ready; also guards red vs prior sum-reads
    if (doIss) issue(tI, gI, v);      // regs free after stage; fly under gemm
    float cI;
    gemm_phase(cI);
    lifp(cI, Ixg, Vg, cg, tP, gP);
  };

  // ---------- t = 0: Iext-only LIF for all 4 groups; prefetch (1,0),(1,1) ----------
  lifp(0.0f, Ix0, V0, c0, 0, 0);
  lifp(0.0f, Ix1, V1, c1, 0, 1);
  lifp(0.0f, Ix2, V2, c2, 0, 2);
  lifp(0.0f, Ix3, V3, c3, 0, 3);
  issue(1, 0, vqE);
  issue(1, 1, vqO);

  for (int t = 1; t < T_STEPS; ++t) {
    const bool nl = (t < T_STEPS - 1);
    phase(t, 0, Ix0, V0, c0, vqE, t, 2, true);       // prefetch (t,2)
    phase(t, 1, Ix1, V1, c1, vqO, t, 3, true);       // prefetch (t,3)
    phase(t, 2, Ix2, V2, c2, vqE, t + 1, 0, nl);     // prefetch (t+1,0)
    phase(t, 3, Ix3, V3, c3, vqO, t + 1, 1, nl);     // prefetch (t+1,1)
  }

  // ---------- write firing rates ----------
  out[(size_t)(gp * 64 +  0 + orow) * N_NEU + n0 + ocol] = (float)c0 * 0.015625f;
  out[(size_t)(gp * 64 + 16 + orow) * N_NEU + n0 + ocol] = (float)c1 * 0.015625f;
  out[(size_t)(gp * 64 + 32 + orow) * N_NEU + n0 + ocol] = (float)c2 * 0.015625f;
  out[(size_t)(gp * 64 + 48 + orow) * N_NEU + n0 + ocol] = (float)c3 * 0.015625f;
}

extern "C" void kernel_launch(void* const* d_in, const int* in_sizes, int n_in,
                              void* d_out, int out_size, void* d_ws, size_t ws_size,
                              hipStream_t stream) {
  (void)in_sizes; (void)n_in; (void)out_size; (void)ws_size;
  const float* ext  = (const float*)d_in[0];
  const float* Win  = (const float*)d_in[1];
  const float* bin  = (const float*)d_in[2];
  const float* adj  = (const float*)d_in[3];
  const float* mask = (const float*)d_in[4];
  unsigned char* ws = (unsigned char*)d_ws;

  _Float16* Wh   = (_Float16*)(ws);
  _Float16* Wl   = (_Float16*)(ws + (size_t)(8u << 20));
  float*    Iext = (float*)   (ws + (size_t)(16u << 20));
  unsigned long long* bmv = (unsigned long long*)(ws + (size_t)(18u << 20));
  float* out = (float*)d_out;

  hipLaunchKernelGGL(k_wsplit, dim3(2048), dim3(256), 0, stream, adj, mask, Wh, Wl, bmv);
  hipLaunchKernelGGL(k_iext,   dim3(128),  dim3(256), 0, stream, ext, Win, bin, Iext);
  hipLaunchKernelGGL(k_fused12, dim3(256), dim3(512), 0, stream,
                     Wh, Wl, Iext, bmv, out);
}

// Round 16
// 393.655 us; speedup vs baseline: 1.6491x; 1.1205x over previous
//
#include <hip/hip_runtime.h>
#include <cstdint>
#include <cstddef>

#define N_NEU 2048
#define D_IN  1024
#define T_STEPS 64

typedef _Float16 f16x8 __attribute__((ext_vector_type(8)));
typedef _Float16 f16x4 __attribute__((ext_vector_type(4)));
typedef float    f32x4 __attribute__((ext_vector_type(4)));
typedef float    f32x16 __attribute__((ext_vector_type(16)));
typedef unsigned u32x4 __attribute__((ext_vector_type(4)));

#define MFMA32(a, b, c) __builtin_amdgcn_mfma_f32_32x32x16_f16((a), (b), (c), 0, 0, 0)

// ---------------- ws layout (bytes) ----------------
// Wh   [2048][2048] f16   @ 0       (8 MB)
// Wl   [2048][2048] f16   @ 8 MB    (8 MB)
// Iext [256][2048]  f32   @ 16 MB   (2 MB)
// bmv  u64[2][256][64]    @ 18 MB   (256 KB)  (tag<<32)|bits: word (row, n/32), bit n%32

// 8 bits -> 8 f16 (0.0/1.0) via multiply-spread: 4 VALU/word.
__device__ inline f16x8 expand8(unsigned b) {
  u32x4 t;
#pragma unroll
  for (int i = 0; i < 4; ++i) {
    unsigned m = (b >> (2 * i)) & 3u;
    unsigned s = (m | (m << 15)) & 0x00010001u;
    t[i] = s * 0x3C00u;
  }
  return __builtin_bit_cast(f16x8, t);
}

// Split W_eff = adj*mask into f16 hi + f16 lo' (w ~= hi + lo'/4096). Zeroes bmv (replay!).
__global__ __launch_bounds__(256) void k_wsplit(const float* __restrict__ adj,
                                                const float* __restrict__ mask,
                                                _Float16* __restrict__ Wh,
                                                _Float16* __restrict__ Wl,
                                                unsigned long long* __restrict__ bmv) {
  const int idx = blockIdx.x * 256 + threadIdx.x;
  if (idx < 2 * 256 * 64) bmv[idx] = 0ull;
  const int total4 = (N_NEU * N_NEU) / 4;
  for (int i = idx; i < total4; i += gridDim.x * 256) {
    float4 a = ((const float4*)adj)[i];
    float4 m = ((const float4*)mask)[i];
    float w0 = a.x * m.x, w1 = a.y * m.y, w2 = a.z * m.z, w3 = a.w * m.w;
    f16x4 h, lo;
    h[0] = (_Float16)w0; lo[0] = (_Float16)((w0 - (float)h[0]) * 4096.0f);
    h[1] = (_Float16)w1; lo[1] = (_Float16)((w1 - (float)h[1]) * 4096.0f);
    h[2] = (_Float16)w2; lo[2] = (_Float16)((w2 - (float)h[2]) * 4096.0f);
    h[3] = (_Float16)w3; lo[3] = (_Float16)((w3 - (float)h[3]) * 4096.0f);
    ((f16x4*)Wh)[i] = h;
    ((f16x4*)Wl)[i] = lo;
  }
}

// I_ext = ext @ W_in^T + b_in, plain fp32. Proven absmax 0.0 (r1/r5-r15).
__global__ __launch_bounds__(256) void k_iext(const float* __restrict__ ext,
                                              const float* __restrict__ Win,
                                              const float* __restrict__ bin,
                                              float* __restrict__ Iext) {
  __shared__ float At[32][68];
  __shared__ float Bt[32][68];
  const int tid = threadIdx.x;
  const int b0 = (blockIdx.x & 3) * 64;
  const int n0 = (blockIdx.x >> 2) * 64;
  const int tx = tid & 15, ty = tid >> 4;
  float acc[4][4] = {};
  for (int kt = 0; kt < D_IN / 32; ++kt) {
    const int k0 = kt * 32;
#pragma unroll
    for (int i = 0; i < 8; ++i) {
      int e = tid + i * 256;
      int kk = e & 31, row = e >> 5;
      At[kk][row] = ext[(size_t)(b0 + row) * D_IN + k0 + kk];
      Bt[kk][row] = Win[(size_t)(n0 + row) * D_IN + k0 + kk];
    }
    __syncthreads();
    for (int kk = 0; kk < 32; ++kk) {
      f32x4 a = *(const f32x4*)&At[kk][ty * 4];
      f32x4 b = *(const f32x4*)&Bt[kk][tx * 4];
#pragma unroll
      for (int i = 0; i < 4; ++i)
#pragma unroll
        for (int j = 0; j < 4; ++j) acc[i][j] += a[i] * b[j];
    }
    __syncthreads();
  }
#pragma unroll
  for (int i = 0; i < 4; ++i)
#pragma unroll
    for (int j = 0; j < 4; ++j)
      Iext[(size_t)(b0 + ty * 4 + i) * N_NEU + n0 + tx * 4 + j] = acc[i][j] + bin[n0 + tx * 4 + j];
}

// Persistent fused LIF kernel, dual-group zero-barrier dataflow (r14 structure) with
// 32x32x16 MFMA: half the MFMA instructions for the same MACs.
// 256 blocks x 512 thr (1/CU). Block (gp 0..3, ns 0..63): groups gA=gp, gB=gp+4 (32 rows)
// x cols ns*32..+32. 8 waves split K (256 each). Wh+Wl resident in VGPRs (128 regs).
__global__ __launch_bounds__(512, 2) void k_fused13(
    const _Float16* __restrict__ Wh, const _Float16* __restrict__ Wl,
    const float* __restrict__ Iext, unsigned long long* __restrict__ bmv,
    float* __restrict__ out) {
  __shared__ float red[8 * 32 * 33];   // 33 KB: [wave][col][row], stride 33 (conflict-free)
  __shared__ unsigned bmA[32 * 64];    // 8 KB group-A spike bits (swizzled)
  __shared__ unsigned bmB[32 * 64];    // 8 KB group-B spike bits

  const int tid = threadIdx.x;
  const int lane = tid & 63;
  const int kw = tid >> 6;        // wave id = split-K index 0..7
  const int l31 = lane & 31;
  const int hl = lane >> 5;       // 0/1: k-half within MFMA
  const int gp = blockIdx.x >> 6; // 0..3
  const int ns = blockIdx.x & 63; // 0..63
  const int n0 = ns * 32;
  const int gA = gp, gB = gp + 4;
  const float inv4096 = 1.0f / 4096.0f;

  // ---------- per-thread Iext (mapping identical to r14) ----------
  float IxA[2], IxB[2];
#pragma unroll
  for (int j = 0; j < 2; ++j) {
    IxA[j] = Iext[(size_t)(gA * 32 + j * 16 + (tid >> 5)) * N_NEU + n0 + (tid & 31)];
    IxB[j] = Iext[(size_t)(gB * 32 + j * 16 + (tid >> 5)) * N_NEU + n0 + (tid & 31)];
  }

  // ---------- resident Wh + Wl fragments for 32x32x16 ----------
  // B layout: lane holds col = lane&31, k = (lane>>5)*8 + reg (same convention as the
  // proven 16x16x32 usage: row=lane&15, k=(lane>>4)*8+reg).
  const _Float16* whb = Wh + (size_t)(n0 + l31) * N_NEU + kw * 256 + hl * 8;
  const _Float16* wlb = Wl + (size_t)(n0 + l31) * N_NEU + kw * 256 + hl * 8;
  f16x8 whf[16], wlf[16];
#pragma unroll
  for (int kcl = 0; kcl < 16; ++kcl) {
    whf[kcl] = *(const f16x8*)(whb + kcl * 16);
    wlf[kcl] = *(const f16x8*)(wlb + kcl * 16);
  }

  float VA[2] = {0.f, 0.f}, VB[2] = {0.f, 0.f};
  unsigned cA[2] = {0u, 0u}, cB[2] = {0u, 0u};
  unsigned long long vA[4], vB[4];

  // speculative one-shot load of group g's 2048-word slab (4 coalesced u64/thread)
  auto spec_issue = [&](int g, int buf, unsigned long long (&v)[4]) {
    const unsigned long long* src = bmv + (size_t)buf * 16384 + (size_t)g * 2048 + tid;
#pragma unroll
    for (int i = 0; i < 4; ++i)
      v[i] = __hip_atomic_load(src + (size_t)i * 512, __ATOMIC_RELAXED, __HIP_MEMORY_SCOPE_AGENT);
  };
  // validate tags; retry only stale words (rare: issued a compute-phase ago)
  auto check_retry = [&](int g, int buf, unsigned want, unsigned long long (&v)[4]) {
    const unsigned long long* src = bmv + (size_t)buf * 16384 + (size_t)g * 2048 + tid;
    unsigned need = 0u;
#pragma unroll
    for (int i = 0; i < 4; ++i)
      if ((unsigned)(v[i] >> 32) != want) need |= 1u << i;
    while (need) {
      __builtin_amdgcn_s_sleep(2);
#pragma unroll
      for (int i = 0; i < 4; ++i)
        if (need & (1u << i)) {
          v[i] = __hip_atomic_load(src + (size_t)i * 512,
                                   __ATOMIC_RELAXED, __HIP_MEMORY_SCOPE_AGENT);
          if ((unsigned)(v[i] >> 32) == want) need &= ~(1u << i);
        }
    }
  };
  // stage bits into swizzled LDS: word nsw of row r at [r*64 + (nsw ^ ((r&15)<<2))]
  auto stage = [&](unsigned* bm, const unsigned long long (&v)[4]) {
#pragma unroll
    for (int i = 0; i < 4; ++i) {
      const int w = i * 512 + tid, r = w >> 6, nsw = w & 63;
      bm[r * 64 + (nsw ^ ((r & 15) << 2))] = (unsigned)v[i];
    }
  };
  // K-loop (32x32x16, 16 kcl x 2 terms) + flat 8-slab split-K tree (ONE sync) -> cI[2]
  auto gemm = [&](const unsigned* bm, float (&cI)[2]) {
    f32x16 acch = {0.f, 0.f, 0.f, 0.f, 0.f, 0.f, 0.f, 0.f,
                   0.f, 0.f, 0.f, 0.f, 0.f, 0.f, 0.f, 0.f};
    f32x16 accl = acch;
    // A bits: row = lane&31, k-byte(kcl) = 2*kcl + hl -> word kcl>>1, shift hl*8+(kcl&1)*16
    const int arow = l31;
    const int swz = (arow & 15) << 2;
    const u32x4 q0 = *(const u32x4*)&bm[arow * 64 + ((kw * 8) ^ swz)];
    const u32x4 q1 = *(const u32x4*)&bm[arow * 64 + (((kw * 8) | 4) ^ swz)];
    const unsigned sh0 = hl * 8;
#pragma unroll
    for (int kcl = 0; kcl < 16; ++kcl) {
      const unsigned word = (kcl < 8) ? q0[kcl >> 1] : q1[(kcl >> 1) - 4];
      const f16x8 a = expand8((word >> (sh0 + ((kcl & 1) << 4))) & 0xFFu);
      acch = MFMA32(a, whf[kcl], acch);
      accl = MFMA32(a, wlf[kcl], accl);
    }
    f32x16 cb = acch + accl * inv4096;
    // C layout: col = lane&31, row = (reg&3) + 8*(reg>>2) + 4*hl
    const int hl4 = hl * 4;
#pragma unroll
    for (int rg = 0; rg < 4; ++rg) {
      f32x4 part = {cb[rg * 4 + 0], cb[rg * 4 + 1], cb[rg * 4 + 2], cb[rg * 4 + 3]};
      *(f32x4*)&red[(kw * 32 + l31) * 33 + rg * 8 + hl4] = part;
    }
    __syncthreads();
#pragma unroll
    for (int j = 0; j < 2; ++j) {
      const int o = j * 512 + tid;
      const int row = o >> 5, col = o & 31;
      float s = 0.0f;
#pragma unroll
      for (int p = 0; p < 8; ++p) s += red[(p * 32 + col) * 33 + row];
      cI[j] = s;
    }
  };
  // LIF + tagged spike stores (tag and bits in ONE u64: single-copy-atomic)
  auto lif = [&](const float (&cI)[2], const float (&Ix)[2], float (&V)[2],
                 unsigned (&cnt)[2], int g, int nbuf, unsigned tag, bool dostore) {
#pragma unroll
    for (int j = 0; j < 2; ++j) {
      float I = cI[j] + Ix[j];
      float v = 0.9f * V[j] + I;
      bool sp = (v - 1.0f) >= 0.0f;
      V[j] = sp ? 0.0f : v;
      cnt[j] += sp ? 1u : 0u;
      if (dostore) {
        unsigned long long ba = __ballot(sp);
        const int rowf = g * 32 + j * 16 + kw * 2;  // lanes 0-31: rowf, 32-63: rowf+1
        const unsigned long long tg = ((unsigned long long)tag) << 32;
        if (lane == 0)
          __hip_atomic_store(bmv + (size_t)nbuf * 16384 + (size_t)rowf * 64 + ns,
                             tg | (unsigned)ba, __ATOMIC_RELAXED, __HIP_MEMORY_SCOPE_AGENT);
        else if (lane == 32)
          __hip_atomic_store(bmv + (size_t)nbuf * 16384 + (size_t)(rowf + 1) * 64 + ns,
                             tg | (unsigned)(ba >> 32), __ATOMIC_RELAXED, __HIP_MEMORY_SCOPE_AGENT);
      }
    }
  };

  // ---------- t = 0: Iext-only LIF; spikes tagged 1 -> buf 1; prefetch A ----------
  {
    const float cz[2] = {0.f, 0.f};
    lif(cz, IxA, VA, cA, gA, 1, 1u, true);
    lif(cz, IxB, VB, cB, gB, 1, 1u, true);
    spec_issue(gA, 1, vA);
  }

  for (int t = 1; t < T_STEPS; ++t) {
    const int cbuf = t & 1, nbuf = (t + 1) & 1;
    const bool last = (t == T_STEPS - 1);
    float cI[2];

    // ---- phase A ----
    check_retry(gA, cbuf, (unsigned)t, vA);
    stage(bmA, vA);
    __syncthreads();
    spec_issue(gB, cbuf, vB);            // in flight under gemm(A)
    gemm(bmA, cI);
    lif(cI, IxA, VA, cA, gA, nbuf, (unsigned)(t + 1), !last);

    // ---- phase B ----
    check_retry(gB, cbuf, (unsigned)t, vB);
    stage(bmB, vB);
    __syncthreads();
    if (!last) spec_issue(gA, nbuf, vA); // in flight under gemm(B)
    gemm(bmB, cI);
    lif(cI, IxB, VB, cB, gB, nbuf, (unsigned)(t + 1), !last);
  }

  // ---------- write firing rates ----------
#pragma unroll
  for (int j = 0; j < 2; ++j) {
    const int rA = gA * 32 + j * 16 + (tid >> 5);
    const int rB = gB * 32 + j * 16 + (tid >> 5);
    out[(size_t)rA * N_NEU + n0 + (tid & 31)] = (float)cA[j] * 0.015625f;
    out[(size_t)rB * N_NEU + n0 + (tid & 31)] = (float)cB[j] * 0.015625f;
  }
}

extern "C" void kernel_launch(void* const* d_in, const int* in_sizes, int n_in,
                              void* d_out, int out_size, void* d_ws, size_t ws_size,
                              hipStream_t stream) {
  (void)in_sizes; (void)n_in; (void)out_size; (void)ws_size;
  const float* ext  = (const float*)d_in[0];
  const float* Win  = (const float*)d_in[1];
  const float* bin  = (const float*)d_in[2];
  const float* adj  = (const float*)d_in[3];
  const float* mask = (const float*)d_in[4];
  unsigned char* ws = (unsigned char*)d_ws;

  _Float16* Wh   = (_Float16*)(ws);
  _Float16* Wl   = (_Float16*)(ws + (size_t)(8u << 20));
  float*    Iext = (float*)   (ws + (size_t)(16u << 20));
  unsigned long long* bmv = (unsigned long long*)(ws + (size_t)(18u << 20));
  float* out = (float*)d_out;

  hipLaunchKernelGGL(k_wsplit, dim3(2048), dim3(256), 0, stream, adj, mask, Wh, Wl, bmv);
  hipLaunchKernelGGL(k_iext,   dim3(128),  dim3(256), 0, stream, ext, Win, bin, Iext);
  hipLaunchKernelGGL(k_fused13, dim3(256), dim3(512), 0, stream,
                     Wh, Wl, Iext, bmv, out);
}